// Round 1
// baseline (1082.075 us; speedup 1.0000x reference)
//
#include <hip/hip_runtime.h>

#define B_  32
#define L_  2048
#define D_  1024
#define NW_ 409
#define W_  5
#define T_  11
#define H_  8
#define HD_ 128
#define MQ  (B_*NW_)   // 13088
#define MQP 13184      // 103*128 (padded M for out-proj/q GEMMs)

typedef __attribute__((ext_vector_type(4))) float f32x4;
typedef __attribute__((ext_vector_type(8))) __bf16 bf16x8;

__device__ __forceinline__ float b2f(unsigned short u) {
  union { unsigned int i; float f; } x; x.i = ((unsigned int)u) << 16; return x.f;
}
__device__ __forceinline__ unsigned short f2b(float f) {
  union { float f; unsigned int i; } x; x.f = f;
  unsigned int r = (x.i + 0x7FFFu + ((x.i >> 16) & 1u)) >> 16;
  return (unsigned short)r;
}

__device__ __forceinline__ void async_copy16(const void* g, void* l) {
  __builtin_amdgcn_global_load_lds(
      (const __attribute__((address_space(1))) void*)g,
      (__attribute__((address_space(3))) void*)l, 16, 0, 0);
}

// ---------------- fp32 -> bf16 convert (vectorized) ----------------
__global__ void cvt_kernel(const float* __restrict__ in,
                           unsigned short* __restrict__ out, int n4) {
  int i = blockIdx.x * 256 + threadIdx.x;
  if (i >= n4) return;
  float4 v = ((const float4*)in)[i];
  ushort4 o;
  o.x = f2b(v.x); o.y = f2b(v.y); o.z = f2b(v.z); o.w = f2b(v.w);
  ((ushort4*)out)[i] = o;
}

// ---------------- gather query rows (window centers) ----------------
__global__ void gather_q_kernel(const unsigned short* __restrict__ x,
                                unsigned short* __restrict__ xq) {
  int m = blockIdx.x;            // 0..MQP-1
  int t = threadIdx.x;           // 128 threads, 8 bf16 (16B) each
  uint4 v = make_uint4(0, 0, 0, 0);
  if (m < MQ) {
    int b = m / NW_, n = m - b * NW_;
    v = ((const uint4*)(x + ((size_t)b * L_ + (size_t)(W_ * n + W_)) * D_))[t];
  }
  ((uint4*)(xq + (size_t)m * D_))[t] = v;
}

// ---------------- NT bf16 GEMM, m97-style ----------------
// C[M,N] = A[M,K] @ Bw[N,K]^T (+bias[N]); 128x128 tile, BK=32, 256 thr = 4 waves 2x2
template<int WF32>
__global__ __launch_bounds__(256)
void gemm_bt_kernel(const unsigned short* __restrict__ A,
                    const unsigned short* __restrict__ Bw,
                    void* __restrict__ C,
                    const float* __restrict__ bias,
                    int N, int K) {
  __shared__ unsigned short sA[128 * 32];
  __shared__ unsigned short sB[128 * 32];
  const int tid = threadIdx.x;
  const int row0 = blockIdx.x * 128;
  const int col0 = blockIdx.y * 128;
  const int wave = tid >> 6, lane = tid & 63;
  const int wm = wave & 1, wn = wave >> 1;
  // staging: chunk c -> row c>>2, col8 (c&3)*8; LDS contiguous at c*8 elems
  const int c0 = tid, c1 = tid + 256;
  const int ar0 = c0 >> 2, ac0 = (c0 & 3) << 3;
  const int ar1 = c1 >> 2, ac1 = (c1 & 3) << 3;
  const int lrow = lane & 15;
  const int lk = (lane >> 4) << 3;

  f32x4 acc[4][4];
#pragma unroll
  for (int i = 0; i < 4; i++)
#pragma unroll
    for (int j = 0; j < 4; j++) acc[i][j] = (f32x4)0.0f;

  const unsigned short* Ar0 = A + (size_t)(row0 + ar0) * K + ac0;
  const unsigned short* Ar1 = A + (size_t)(row0 + ar1) * K + ac1;
  const unsigned short* Br0 = Bw + (size_t)(col0 + ar0) * K + ac0;
  const unsigned short* Br1 = Bw + (size_t)(col0 + ar1) * K + ac1;

  for (int kt = 0; kt < K; kt += 32) {
    async_copy16(Ar0 + kt, &sA[c0 * 8]);
    async_copy16(Ar1 + kt, &sA[c1 * 8]);
    async_copy16(Br0 + kt, &sB[c0 * 8]);
    async_copy16(Br1 + kt, &sB[c1 * 8]);
    __syncthreads();   // drains vmcnt(0) before LDS reads
    bf16x8 af[4], bfr[4];
#pragma unroll
    for (int i = 0; i < 4; i++)
      af[i] = *(const bf16x8*)&sA[(wm * 64 + i * 16 + lrow) * 32 + lk];
#pragma unroll
    for (int j = 0; j < 4; j++)
      bfr[j] = *(const bf16x8*)&sB[(wn * 64 + j * 16 + lrow) * 32 + lk];
#pragma unroll
    for (int i = 0; i < 4; i++)
#pragma unroll
      for (int j = 0; j < 4; j++)
        acc[i][j] = __builtin_amdgcn_mfma_f32_16x16x32_bf16(af[i], bfr[j], acc[i][j], 0, 0, 0);
    __syncthreads();
  }

  const int crow = (lane >> 4) << 2;  // C/D: col=lane&15, row=quad*4+reg (m89/m91)
  const int ccol = lane & 15;
#pragma unroll
  for (int i = 0; i < 4; i++) {
#pragma unroll
    for (int j = 0; j < 4; j++) {
      int gc = col0 + wn * 64 + j * 16 + ccol;
      float bv = bias ? bias[gc] : 0.0f;
#pragma unroll
      for (int r = 0; r < 4; r++) {
        int gr = row0 + wm * 64 + i * 16 + crow + r;
        float v = acc[i][j][r] + bv;
        if (WF32) ((float*)C)[(size_t)gr * N + gc] = v;
        else ((unsigned short*)C)[(size_t)gr * N + gc] = f2b(v);
      }
    }
  }
}

// ---------------- windowed attention (one block per (b,n)) ----------------
__global__ __launch_bounds__(256)
void attn_kernel(const unsigned short* __restrict__ q,
                 const unsigned short* __restrict__ kv,
                 unsigned short* __restrict__ o) {
  __shared__ unsigned short sQ[D_];
  __shared__ unsigned short sK[T_ * D_];
  __shared__ unsigned short sV[T_ * D_];
  __shared__ float sS[H_ * T_];
  __shared__ float sAttn[H_ * T_];
  const int m = blockIdx.x;       // b*NW_+n
  const int b = m / NW_, n = m - b * NW_;
  const int tid = threadIdx.x;

  if (tid < 128)
    ((uint4*)sQ)[tid] = ((const uint4*)(q + (size_t)m * D_))[tid];
  for (int it = tid; it < T_ * 128; it += 256) {
    int t = it >> 7, c = it & 127;
    int pos = W_ * n + t;
    uint4 kvec = make_uint4(0, 0, 0, 0), vvec = make_uint4(0, 0, 0, 0);
    if (pos < L_) {  // padded rows: k=v=0 -> score 0, matches reference (bias=0)
      const uint4* src = (const uint4*)(kv + ((size_t)b * L_ + pos) * 2048);
      kvec = src[c];
      vvec = src[c + 128];
    }
    ((uint4*)sK)[t * 128 + c] = kvec;
    ((uint4*)sV)[t * 128 + c] = vvec;
  }
  __syncthreads();

  if (tid < H_ * T_) {
    int h = tid / T_, t = tid - h * T_;
    const unsigned short* qh = sQ + h * HD_;
    const unsigned short* kh = sK + t * D_ + h * HD_;
    float s = 0.f;
#pragma unroll 8
    for (int d = 0; d < HD_; d++) s += b2f(qh[d]) * b2f(kh[d]);
    sS[tid] = s * 0.08838834764831845f;  // 1/sqrt(128)
  }
  __syncthreads();

  if (tid < H_) {
    float mx = -1e30f;
    for (int t = 0; t < T_; t++) mx = fmaxf(mx, sS[tid * T_ + t]);
    float e[T_], sum = 0.f;
    for (int t = 0; t < T_; t++) { e[t] = expf(sS[tid * T_ + t] - mx); sum += e[t]; }
    float inv = 1.f / sum;
    for (int t = 0; t < T_; t++) sAttn[tid * T_ + t] = e[t] * inv;
  }
  __syncthreads();

#pragma unroll
  for (int rep = 0; rep < 4; rep++) {
    int d = tid + rep * 256;
    int h = d >> 7;
    float accv = 0.f;
#pragma unroll
    for (int t = 0; t < T_; t++) accv += sAttn[h * T_ + t] * b2f(sV[t * D_ + d]);
    o[(size_t)m * D_ + d] = f2b(accv);
  }
}

// ---------------- fill output with log(0.5) ----------------
__global__ void fill_kernel(float* __restrict__ out) {
  int i = blockIdx.x * 256 + threadIdx.x;
  out[i] = -0.69314718055994531f;
}

// ---------------- 2-class head + log_softmax, scatter at rows b*L + 5n ----------------
__global__ __launch_bounds__(256)
void probs_kernel(const float* __restrict__ feat, const float* __restrict__ ow,
                  const float* __restrict__ ob, float* __restrict__ out) {
  const int wave = threadIdx.x >> 6, lane = threadIdx.x & 63;
  const int m = blockIdx.x * 4 + wave;  // grid exact: 3272*4 = 13088
  const float* f = feat + (size_t)m * D_;
  float s0 = 0.f, s1 = 0.f;
  for (int d = lane; d < D_; d += 64) {
    float v = f[d];
    s0 += v * ow[d];
    s1 += v * ow[D_ + d];
  }
  for (int off = 32; off > 0; off >>= 1) {
    s0 += __shfl_down(s0, off);
    s1 += __shfl_down(s1, off);
  }
  if (lane == 0) {
    float p0 = s0 + ob[0], p1 = s1 + ob[1];
    float mx = fmaxf(p0, p1);
    float lse = mx + logf(expf(p0 - mx) + expf(p1 - mx));
    int b = m / NW_, n = m - b * NW_;
    size_t row = (size_t)b * L_ + (size_t)(W_ * n);
    out[row * 2 + 0] = p0 - lse;
    out[row * 2 + 1] = p1 - lse;
  }
}

extern "C" void kernel_launch(void* const* d_in, const int* in_sizes, int n_in,
                              void* d_out, int out_size, void* d_ws, size_t ws_size,
                              hipStream_t stream) {
  const float* x          = (const float*)d_in[0];
  const float* in_proj_w  = (const float*)d_in[1];
  const float* in_proj_b  = (const float*)d_in[2];
  const float* out_proj_w = (const float*)d_in[3];
  const float* out_proj_b = (const float*)d_in[4];
  const float* out_w      = (const float*)d_in[5];
  const float* out_b      = (const float*)d_in[6];
  float* out = (float*)d_out;

  // workspace layout (total ~438 MB):
  //   [0, 128MB)        x_bf16  -- dead after kv GEMM; reused for qout/obuf/feat
  //   [128MB, +6MB)     in_proj_w bf16 (wq|wk|wv)
  //   [+2MB)            out_proj_w bf16
  //   [+27MB)           xq (gathered centers, padded to MQP rows)
  //   [+256MB)          kv = K|V bf16, (B*L) x 2048
  char* ws = (char*)d_ws;
  unsigned short* xbf  = (unsigned short*)(ws);
  unsigned short* win  = (unsigned short*)(ws + 134217728);
  unsigned short* wop  = (unsigned short*)(ws + 140509184);
  unsigned short* xq   = (unsigned short*)(ws + 142606336);
  unsigned short* kvb  = (unsigned short*)(ws + 169607168);
  unsigned short* qout = (unsigned short*)(ws);              // aliases dead xbf
  unsigned short* obuf = (unsigned short*)(ws + 27262976);
  float*          feat = (float*)(ws + 54525952);

  cvt_kernel<<<65536, 256, 0, stream>>>(x, xbf, 16777216);
  cvt_kernel<<<3072, 256, 0, stream>>>(in_proj_w, win, 786432);
  cvt_kernel<<<1024, 256, 0, stream>>>(out_proj_w, wop, 262144);
  gather_q_kernel<<<MQP, 128, 0, stream>>>(xbf, xq);

  dim3 gkv(512, 16);  // M=65536, N=2048 (K|V), K=1024
  gemm_bt_kernel<0><<<gkv, 256, 0, stream>>>(xbf, win + 1048576, kvb,
                                             in_proj_b + 1024, 2048, 1024);
  dim3 gq(103, 8);    // M=13184, N=1024
  gemm_bt_kernel<0><<<gq, 256, 0, stream>>>(xq, win, qout, in_proj_b, 1024, 1024);

  attn_kernel<<<MQ, 256, 0, stream>>>(qout, kvb, obuf);

  gemm_bt_kernel<1><<<gq, 256, 0, stream>>>(obuf, wop, feat, out_proj_b, 1024, 1024);

  fill_kernel<<<1024, 256, 0, stream>>>(out);
  probs_kernel<<<3272, 256, 0, stream>>>(feat, out_w, out_b, out);
}

// Round 2
// 1049.795 us; speedup vs baseline: 1.0307x; 1.0307x over previous
//
#include <hip/hip_runtime.h>

#define B_  32
#define L_  2048
#define D_  1024
#define NW_ 409
#define W_  5
#define T_  11
#define H_  8
#define HD_ 128
#define MQ  (B_*NW_)   // 13088
#define MQP 13184      // 103*128 (padded M for out-proj/q GEMMs)

typedef __attribute__((ext_vector_type(4))) float f32x4;
typedef __attribute__((ext_vector_type(8))) __bf16 bf16x8;

__device__ __forceinline__ float b2f(unsigned short u) {
  union { unsigned int i; float f; } x; x.i = ((unsigned int)u) << 16; return x.f;
}
__device__ __forceinline__ unsigned short f2b(float f) {
  union { float f; unsigned int i; } x; x.f = f;
  unsigned int r = (x.i + 0x7FFFu + ((x.i >> 16) & 1u)) >> 16;
  return (unsigned short)r;
}
// unpack packed bf16 pair (low elem = low 16 bits)
__device__ __forceinline__ float2 bf2x(unsigned int u) {
  union { unsigned int i; float f; } lo, hi;
  lo.i = u << 16; hi.i = u & 0xffff0000u;
  return make_float2(lo.f, hi.f);
}

__device__ __forceinline__ void async_copy16(const void* g, void* l) {
  __builtin_amdgcn_global_load_lds(
      (const __attribute__((address_space(1))) void*)g,
      (__attribute__((address_space(3))) void*)l, 16, 0, 0);
}

// ---------------- fp32 -> bf16 convert (vectorized) ----------------
__global__ void cvt_kernel(const float* __restrict__ in,
                           unsigned short* __restrict__ out, int n4) {
  int i = blockIdx.x * 256 + threadIdx.x;
  if (i >= n4) return;
  float4 v = ((const float4*)in)[i];
  ushort4 o;
  o.x = f2b(v.x); o.y = f2b(v.y); o.z = f2b(v.z); o.w = f2b(v.w);
  ((ushort4*)out)[i] = o;
}

// ---------------- gather query rows (window centers) ----------------
__global__ void gather_q_kernel(const unsigned short* __restrict__ x,
                                unsigned short* __restrict__ xq) {
  int m = blockIdx.x;            // 0..MQP-1
  int t = threadIdx.x;           // 128 threads, 8 bf16 (16B) each
  uint4 v = make_uint4(0, 0, 0, 0);
  if (m < MQ) {
    int b = m / NW_, n = m - b * NW_;
    v = ((const uint4*)(x + ((size_t)b * L_ + (size_t)(W_ * n + W_)) * D_))[t];
  }
  ((uint4*)(xq + (size_t)m * D_))[t] = v;
}

// ---------------- NT bf16 GEMM, m97-style + bank-conflict swizzle ----------------
// C[M,N] = A[M,K] @ Bw[N,K]^T (+bias[N]); 128x128 tile, BK=32, 256 thr = 4 waves 2x2
// blockIdx.x = col tile (fastest -> col tiles of one row-tile run together, A reused in L2)
// LDS chunk swizzle: chunk c holds (r=c>>2, kc=((c&3)-(r>>1))&3); read addr for (rr,kcr)
// is rr*32 + ((kcr+(rr>>1))&3)*8 -> each 16-lane phase covers all 8 bank-quads 2x (free).
template<int WF32>
__global__ __launch_bounds__(256)
void gemm_bt_kernel(const unsigned short* __restrict__ A,
                    const unsigned short* __restrict__ Bw,
                    void* __restrict__ C,
                    const float* __restrict__ bias,
                    int N, int K) {
  __shared__ unsigned short sA[128 * 32];
  __shared__ unsigned short sB[128 * 32];
  const int tid = threadIdx.x;
  const int row0 = blockIdx.y * 128;
  const int col0 = blockIdx.x * 128;
  const int wave = tid >> 6, lane = tid & 63;
  const int wm = wave & 1, wn = wave >> 1;
  // staging: thread tid fetches chunks c0=tid, c1=tid+256 (swizzled source coords)
  const int c0 = tid, c1 = tid + 256;
  const int r0s = c0 >> 2, kc0 = ((c0 & 3) - (r0s >> 1)) & 3;
  const int r1s = c1 >> 2, kc1 = ((c1 & 3) - (r1s >> 1)) & 3;
  const int lrow = lane & 15;
  const int kcr = lane >> 4;

  int offA[4], offB[4];
#pragma unroll
  for (int i = 0; i < 4; i++) {
    int ra = wm * 64 + i * 16 + lrow;
    offA[i] = ra * 32 + (((kcr + (ra >> 1)) & 3) << 3);
    int rb = wn * 64 + i * 16 + lrow;
    offB[i] = rb * 32 + (((kcr + (rb >> 1)) & 3) << 3);
  }

  f32x4 acc[4][4];
#pragma unroll
  for (int i = 0; i < 4; i++)
#pragma unroll
    for (int j = 0; j < 4; j++) acc[i][j] = (f32x4)0.0f;

  const unsigned short* Ar0 = A + (size_t)(row0 + r0s) * K + kc0 * 8;
  const unsigned short* Ar1 = A + (size_t)(row0 + r1s) * K + kc1 * 8;
  const unsigned short* Br0 = Bw + (size_t)(col0 + r0s) * K + kc0 * 8;
  const unsigned short* Br1 = Bw + (size_t)(col0 + r1s) * K + kc1 * 8;

  for (int kt = 0; kt < K; kt += 32) {
    async_copy16(Ar0 + kt, &sA[c0 * 8]);
    async_copy16(Ar1 + kt, &sA[c1 * 8]);
    async_copy16(Br0 + kt, &sB[c0 * 8]);
    async_copy16(Br1 + kt, &sB[c1 * 8]);
    __syncthreads();   // drains vmcnt(0) before LDS reads
    bf16x8 af[4], bfr[4];
#pragma unroll
    for (int i = 0; i < 4; i++) af[i] = *(const bf16x8*)&sA[offA[i]];
#pragma unroll
    for (int j = 0; j < 4; j++) bfr[j] = *(const bf16x8*)&sB[offB[j]];
#pragma unroll
    for (int i = 0; i < 4; i++)
#pragma unroll
      for (int j = 0; j < 4; j++)
        acc[i][j] = __builtin_amdgcn_mfma_f32_16x16x32_bf16(af[i], bfr[j], acc[i][j], 0, 0, 0);
    __syncthreads();
  }

  const int crow = (lane >> 4) << 2;  // C/D: col=lane&15, row=quad*4+reg (m89/m91)
  const int ccol = lane & 15;
#pragma unroll
  for (int i = 0; i < 4; i++) {
#pragma unroll
    for (int j = 0; j < 4; j++) {
      int gc = col0 + wn * 64 + j * 16 + ccol;
      float bv = bias ? bias[gc] : 0.0f;
#pragma unroll
      for (int r = 0; r < 4; r++) {
        int gr = row0 + wm * 64 + i * 16 + crow + r;
        float v = acc[i][j][r] + bv;
        if (WF32) ((float*)C)[(size_t)gr * N + gc] = v;
        else ((unsigned short*)C)[(size_t)gr * N + gc] = f2b(v);
      }
    }
  }
}

// ---------------- windowed attention (one block per (b,n)) ----------------
__global__ __launch_bounds__(256)
void attn_kernel(const unsigned short* __restrict__ q,
                 const unsigned short* __restrict__ kv,
                 unsigned short* __restrict__ o) {
  __shared__ unsigned short sQ[D_];
  __shared__ unsigned short sK[T_ * D_];
  __shared__ unsigned short sV[T_ * D_];
  __shared__ float sS[H_ * T_];
  __shared__ float sAttn[H_ * T_];
  const int m = blockIdx.x;       // b*NW_+n
  const int b = m / NW_, n = m - b * NW_;
  const int tid = threadIdx.x;

  if (tid < 128)
    ((uint4*)sQ)[tid] = ((const uint4*)(q + (size_t)m * D_))[tid];
  for (int it = tid; it < T_ * 128; it += 256) {
    int t = it >> 7, c = it & 127;
    int pos = W_ * n + t;
    uint4 kvec = make_uint4(0, 0, 0, 0), vvec = make_uint4(0, 0, 0, 0);
    if (pos < L_) {  // padded rows: k=v=0 -> score 0, matches reference (bias=0)
      const uint4* src = (const uint4*)(kv + ((size_t)b * L_ + pos) * 2048);
      kvec = src[c];
      vvec = src[c + 128];
    }
    ((uint4*)sK)[t * 128 + c] = kvec;
    ((uint4*)sV)[t * 128 + c] = vvec;
  }
  __syncthreads();

  // scores: 2 lanes per (h,t) pair, each does a 64-elem dot via 8x uint4 (bf16x8)
  // bank rotation: naive c-order puts all lanes on banks 4c..4c+3 (64-way);
  // rotating start by lane&7 spreads each 16-lane phase over all 8 quads.
  {
    int p = tid >> 1;
    if (p < H_ * T_) {
      int h = p / T_, t = p - h * T_;
      int dbase = h * HD_ + (tid & 1) * 64;
      const uint4* qp = (const uint4*)(sQ + dbase);
      const uint4* kp = (const uint4*)(sK + t * D_ + dbase);
      float s = 0.f;
      int crot = tid & 7;
#pragma unroll
      for (int cc = 0; cc < 8; cc++) {
        int c = (crot + cc) & 7;
        uint4 a = qp[c], k4 = kp[c];
        float2 a0 = bf2x(a.x), b0 = bf2x(k4.x);
        float2 a1 = bf2x(a.y), b1 = bf2x(k4.y);
        float2 a2 = bf2x(a.z), b2 = bf2x(k4.z);
        float2 a3 = bf2x(a.w), b3 = bf2x(k4.w);
        s += a0.x * b0.x + a0.y * b0.y + a1.x * b1.x + a1.y * b1.y;
        s += a2.x * b2.x + a2.y * b2.y + a3.x * b3.x + a3.y * b3.y;
      }
      s += __shfl_down(s, 1);
      if ((tid & 1) == 0) sS[p] = s * 0.08838834764831845f;  // 1/sqrt(128)
    }
  }
  __syncthreads();

  if (tid < H_) {
    float mx = -1e30f;
    for (int t = 0; t < T_; t++) mx = fmaxf(mx, sS[tid * T_ + t]);
    float e[T_], sum = 0.f;
    for (int t = 0; t < T_; t++) { e[t] = expf(sS[tid * T_ + t] - mx); sum += e[t]; }
    float inv = 1.f / sum;
    for (int t = 0; t < T_; t++) sAttn[tid * T_ + t] = e[t] * inv;
  }
  __syncthreads();

  // o: each thread owns 4 contiguous d (ushort4 LDS reads: lanes cover all banks)
  {
    int d4 = tid * 4;
    int h = tid >> 5;
    float a0 = 0.f, a1 = 0.f, a2 = 0.f, a3 = 0.f;
#pragma unroll
    for (int t = 0; t < T_; t++) {
      float w = sAttn[h * T_ + t];
      ushort4 v = *(const ushort4*)(sV + t * D_ + d4);
      a0 += w * b2f(v.x); a1 += w * b2f(v.y);
      a2 += w * b2f(v.z); a3 += w * b2f(v.w);
    }
    ushort4 ov;
    ov.x = f2b(a0); ov.y = f2b(a1); ov.z = f2b(a2); ov.w = f2b(a3);
    *(ushort4*)(o + (size_t)m * D_ + d4) = ov;
  }
}

// ---------------- fill output with log(0.5) ----------------
__global__ void fill_kernel(float* __restrict__ out) {
  int i = blockIdx.x * 256 + threadIdx.x;
  out[i] = -0.69314718055994531f;
}

// ---------------- 2-class head + log_softmax, scatter at rows b*L + 5n ----------------
__global__ __launch_bounds__(256)
void probs_kernel(const float* __restrict__ feat, const float* __restrict__ ow,
                  const float* __restrict__ ob, float* __restrict__ out) {
  const int wave = threadIdx.x >> 6, lane = threadIdx.x & 63;
  const int m = blockIdx.x * 4 + wave;  // grid exact: 3272*4 = 13088
  const float* f = feat + (size_t)m * D_;
  float s0 = 0.f, s1 = 0.f;
  for (int d = lane; d < D_; d += 64) {
    float v = f[d];
    s0 += v * ow[d];
    s1 += v * ow[D_ + d];
  }
  for (int off = 32; off > 0; off >>= 1) {
    s0 += __shfl_down(s0, off);
    s1 += __shfl_down(s1, off);
  }
  if (lane == 0) {
    float p0 = s0 + ob[0], p1 = s1 + ob[1];
    float mx = fmaxf(p0, p1);
    float lse = mx + logf(expf(p0 - mx) + expf(p1 - mx));
    int b = m / NW_, n = m - b * NW_;
    size_t row = (size_t)b * L_ + (size_t)(W_ * n);
    out[row * 2 + 0] = p0 - lse;
    out[row * 2 + 1] = p1 - lse;
  }
}

extern "C" void kernel_launch(void* const* d_in, const int* in_sizes, int n_in,
                              void* d_out, int out_size, void* d_ws, size_t ws_size,
                              hipStream_t stream) {
  const float* x          = (const float*)d_in[0];
  const float* in_proj_w  = (const float*)d_in[1];
  const float* in_proj_b  = (const float*)d_in[2];
  const float* out_proj_w = (const float*)d_in[3];
  const float* out_proj_b = (const float*)d_in[4];
  const float* out_w      = (const float*)d_in[5];
  const float* out_b      = (const float*)d_in[6];
  float* out = (float*)d_out;

  // workspace layout (total ~438 MB):
  //   [0, 128MB)        x_bf16  -- dead after kv GEMM; reused for qout/obuf/feat
  //   [128MB, +6MB)     in_proj_w bf16 (wq|wk|wv)
  //   [+2MB)            out_proj_w bf16
  //   [+27MB)           xq (gathered centers, padded to MQP rows)
  //   [+256MB)          kv = K|V bf16, (B*L) x 2048
  char* ws = (char*)d_ws;
  unsigned short* xbf  = (unsigned short*)(ws);
  unsigned short* win  = (unsigned short*)(ws + 134217728);
  unsigned short* wop  = (unsigned short*)(ws + 140509184);
  unsigned short* xq   = (unsigned short*)(ws + 142606336);
  unsigned short* kvb  = (unsigned short*)(ws + 169607168);
  unsigned short* qout = (unsigned short*)(ws);              // aliases dead xbf
  unsigned short* obuf = (unsigned short*)(ws + 27262976);
  float*          feat = (float*)(ws + 54525952);

  cvt_kernel<<<65536, 256, 0, stream>>>(x, xbf, 16777216);
  cvt_kernel<<<3072, 256, 0, stream>>>(in_proj_w, win, 786432);
  cvt_kernel<<<1024, 256, 0, stream>>>(out_proj_w, wop, 262144);
  gather_q_kernel<<<MQP, 128, 0, stream>>>(xbf, xq);

  dim3 gkv(16, 512);  // x = col tile (fastest), y = row tile; M=65536, N=2048 (K|V)
  gemm_bt_kernel<0><<<gkv, 256, 0, stream>>>(xbf, win + 1048576, kvb,
                                             in_proj_b + 1024, 2048, 1024);
  dim3 gq(8, 103);    // M=13184, N=1024
  gemm_bt_kernel<0><<<gq, 256, 0, stream>>>(xq, win, qout, in_proj_b, 1024, 1024);

  attn_kernel<<<MQ, 256, 0, stream>>>(qout, kvb, obuf);

  gemm_bt_kernel<1><<<gq, 256, 0, stream>>>(obuf, wop, feat, out_proj_b, 1024, 1024);

  fill_kernel<<<512, 256, 0, stream>>>(out);  // exactly out_size=131072 floats
  probs_kernel<<<3272, 256, 0, stream>>>(feat, out_w, out_b, out);
}

// Round 3
// 1034.659 us; speedup vs baseline: 1.0458x; 1.0146x over previous
//
#include <hip/hip_runtime.h>

#define B_  32
#define L_  2048
#define D_  1024
#define NW_ 409
#define W_  5
#define T_  11
#define H_  8
#define HD_ 128
#define MQ  (B_*NW_)   // 13088
#define MQP 13184      // 103*128 (padded M for q GEMM)

typedef __attribute__((ext_vector_type(4))) float f32x4;
typedef __attribute__((ext_vector_type(8))) __bf16 bf16x8;

__device__ __forceinline__ float b2f(unsigned short u) {
  union { unsigned int i; float f; } x; x.i = ((unsigned int)u) << 16; return x.f;
}
__device__ __forceinline__ unsigned short f2b(float f) {
  union { float f; unsigned int i; } x; x.f = f;
  unsigned int r = (x.i + 0x7FFFu + ((x.i >> 16) & 1u)) >> 16;
  return (unsigned short)r;
}
__device__ __forceinline__ float2 bf2x(unsigned int u) {
  union { unsigned int i; float f; } lo, hi;
  lo.i = u << 16; hi.i = u & 0xffff0000u;
  return make_float2(lo.f, hi.f);
}

__device__ __forceinline__ void async_copy16(const void* g, void* l) {
  __builtin_amdgcn_global_load_lds(
      (const __attribute__((address_space(1))) void*)g,
      (__attribute__((address_space(3))) void*)l, 16, 0, 0);
}

// ---------------- fp32 -> bf16 convert (vectorized) ----------------
__global__ void cvt_kernel(const float* __restrict__ in,
                           unsigned short* __restrict__ out, int n4) {
  int i = blockIdx.x * 256 + threadIdx.x;
  if (i >= n4) return;
  float4 v = ((const float4*)in)[i];
  ushort4 o;
  o.x = f2b(v.x); o.y = f2b(v.y); o.z = f2b(v.z); o.w = f2b(v.w);
  ((ushort4*)out)[i] = o;
}

// ---------------- gather query rows (window centers) ----------------
__global__ void gather_q_kernel(const unsigned short* __restrict__ x,
                                unsigned short* __restrict__ xq) {
  int m = blockIdx.x;            // 0..MQP-1
  int t = threadIdx.x;           // 128 threads, 16B each
  uint4 v = make_uint4(0, 0, 0, 0);
  if (m < MQ) {
    int b = m / NW_, n = m - b * NW_;
    v = ((const uint4*)(x + ((size_t)b * L_ + (size_t)(W_ * n + W_)) * D_))[t];
  }
  ((uint4*)(xq + (size_t)m * D_))[t] = v;
}

// ---------------- fused head weights: Wc = out_w @ out_proj_w, bc = out_w@opb + ob ----
__global__ void wc_kernel(const float* __restrict__ ow, const float* __restrict__ opw,
                          const float* __restrict__ opb, const float* __restrict__ ob,
                          float* __restrict__ Wc, float* __restrict__ bc) {
  int d = blockIdx.x * 256 + threadIdx.x;   // 0..2047; c = d>>10
  int c = d >> 10, dd = d & 1023;
  float acc = 0.f;
  for (int e = 0; e < D_; e++) acc += ow[c * D_ + e] * opw[e * D_ + dd];
  Wc[d] = acc;
  if (d < 2) {
    float s = ob[d];
    for (int e = 0; e < D_; e++) s += ow[d * D_ + e] * opb[e];
    bc[d] = s;
  }
}

// ---------------- NT bf16 GEMM, BK=64 (32 MFMA per barrier-pair) ----------------
// C[M,N] = A[M,K] @ Bw[N,K]^T (+bias[N]); 128x128 tile, 256 thr = 4 waves 2x2.
// LDS slot c holds chunk (r=c>>3, kc=((c&7)-r)&7); fragment (rr,kcr) at slot
// rr*8+((kcr+rr)&7) -> each 16-lane phase covers all 8 bank-quads 2x (free).
template<int WF32>
__global__ __launch_bounds__(256)
void gemm_bt_kernel(const unsigned short* __restrict__ A,
                    const unsigned short* __restrict__ Bw,
                    void* __restrict__ C,
                    const float* __restrict__ bias,
                    int N, int K) {
  __shared__ unsigned short sA[128 * 64];
  __shared__ unsigned short sB[128 * 64];
  const int tid = threadIdx.x;
  const int row0 = blockIdx.y * 128;
  const int col0 = blockIdx.x * 128;  // x fastest: col tiles of a row tile share A in L2
  const int wave = tid >> 6, lane = tid & 63;
  const int wm = wave & 1, wn = wave >> 1;
  const int lrow = lane & 15;
  const int kq = lane >> 4;           // 0..3

  int src_r[4], src_kc[4];
#pragma unroll
  for (int u = 0; u < 4; u++) {
    int c = tid + 256 * u;
    src_r[u]  = c >> 3;
    src_kc[u] = ((c & 7) - (c >> 3)) & 7;
  }

  int offA[2][4], offB[2][4];
#pragma unroll
  for (int i = 0; i < 4; i++) {
#pragma unroll
    for (int kh = 0; kh < 2; kh++) {
      int kcr = kh * 4 + kq;
      int ra = wm * 64 + i * 16 + lrow;
      offA[kh][i] = (ra * 8 + ((kcr + ra) & 7)) * 8;
      int rb = wn * 64 + i * 16 + lrow;
      offB[kh][i] = (rb * 8 + ((kcr + rb) & 7)) * 8;
    }
  }

  f32x4 acc[4][4];
#pragma unroll
  for (int i = 0; i < 4; i++)
#pragma unroll
    for (int j = 0; j < 4; j++) acc[i][j] = (f32x4)0.0f;

  const unsigned short* Asrc[4];
  const unsigned short* Bsrc[4];
#pragma unroll
  for (int u = 0; u < 4; u++) {
    Asrc[u] = A  + (size_t)(row0 + src_r[u]) * K + src_kc[u] * 8;
    Bsrc[u] = Bw + (size_t)(col0 + src_r[u]) * K + src_kc[u] * 8;
  }

  for (int kt = 0; kt < K; kt += 64) {
#pragma unroll
    for (int u = 0; u < 4; u++) {
      async_copy16(Asrc[u] + kt, &sA[(tid + 256 * u) * 8]);
      async_copy16(Bsrc[u] + kt, &sB[(tid + 256 * u) * 8]);
    }
    __syncthreads();
#pragma unroll
    for (int kh = 0; kh < 2; kh++) {
      bf16x8 af[4], bfr[4];
#pragma unroll
      for (int i = 0; i < 4; i++) af[i]  = *(const bf16x8*)&sA[offA[kh][i]];
#pragma unroll
      for (int j = 0; j < 4; j++) bfr[j] = *(const bf16x8*)&sB[offB[kh][j]];
#pragma unroll
      for (int i = 0; i < 4; i++)
#pragma unroll
        for (int j = 0; j < 4; j++)
          acc[i][j] = __builtin_amdgcn_mfma_f32_16x16x32_bf16(af[i], bfr[j], acc[i][j], 0, 0, 0);
    }
    __syncthreads();
  }

  const int crow = (lane >> 4) << 2;  // C/D: col=lane&15, row=quad*4+reg (m89/m91)
  const int ccol = lane & 15;
#pragma unroll
  for (int i = 0; i < 4; i++) {
#pragma unroll
    for (int j = 0; j < 4; j++) {
      int gc = col0 + wn * 64 + j * 16 + ccol;
      float bv = bias ? bias[gc] : 0.0f;
#pragma unroll
      for (int r = 0; r < 4; r++) {
        int gr = row0 + wm * 64 + i * 16 + crow + r;
        float v = acc[i][j][r] + bv;
        if (WF32) ((float*)C)[(size_t)gr * N + gc] = v;
        else ((unsigned short*)C)[(size_t)gr * N + gc] = f2b(v);
      }
    }
  }
}

// ---------------- windowed attention, no KV LDS staging ----------------
// Each K/V element is consumed exactly once per window -> read straight from
// global (L2 serves the 2.2x inter-window overlap). LDS only for q + weights.
__global__ __launch_bounds__(256)
void attn_kernel(const unsigned short* __restrict__ q,
                 const unsigned short* __restrict__ kv,
                 unsigned short* __restrict__ o) {
  __shared__ unsigned short sQ[D_];
  __shared__ float sAttn[H_ * T_];
  const int m = blockIdx.x;       // b*NW_+n
  const int b = m / NW_, n = m - b * NW_;
  const int tid = threadIdx.x;
  const size_t rowbase = (size_t)b * L_ * 2048;

  if (tid < 128)
    ((uint4*)sQ)[tid] = ((const uint4*)(q + (size_t)m * D_))[tid];
  __syncthreads();

  // scores: 16 lanes per (h,t); lane reads 8 bf16 of K (256B contiguous per pair)
  {
    const int s = tid & 15, p0 = tid >> 4;
#pragma unroll
    for (int r = 0; r < 6; r++) {
      int pair = r * 16 + p0;           // 0..95, 88 real
      float sc = 0.f;
      if (pair < H_ * T_) {
        int h = pair / T_, t = pair - h * T_;
        int pos = W_ * n + t;
        if (pos < L_) {
          uint4 k4 = *(const uint4*)(kv + rowbase + (size_t)pos * 2048 + h * HD_ + s * 8);
          uint4 q4 = *(const uint4*)(sQ + h * HD_ + s * 8);
          float2 a0 = bf2x(q4.x), b0 = bf2x(k4.x);
          float2 a1 = bf2x(q4.y), b1 = bf2x(k4.y);
          float2 a2 = bf2x(q4.z), b2 = bf2x(k4.z);
          float2 a3 = bf2x(q4.w), b3 = bf2x(k4.w);
          sc = a0.x * b0.x + a0.y * b0.y + a1.x * b1.x + a1.y * b1.y
             + a2.x * b2.x + a2.y * b2.y + a3.x * b3.x + a3.y * b3.y;
        }
      }
      sc += __shfl_down(sc, 8);
      sc += __shfl_down(sc, 4);
      sc += __shfl_down(sc, 2);
      sc += __shfl_down(sc, 1);
      if (pair < H_ * T_ && s == 0)
        sAttn[pair] = sc * 0.08838834764831845f;  // 1/sqrt(128)
    }
  }
  __syncthreads();

  if (tid < H_) {
    float sv[T_];
    float mx = -1e30f;
    for (int t = 0; t < T_; t++) { sv[t] = sAttn[tid * T_ + t]; mx = fmaxf(mx, sv[t]); }
    float sum = 0.f;
    for (int t = 0; t < T_; t++) { sv[t] = expf(sv[t] - mx); sum += sv[t]; }
    float inv = 1.f / sum;
    for (int t = 0; t < T_; t++) sAttn[tid * T_ + t] = sv[t] * inv;
  }
  __syncthreads();

  // o: thread owns 4 contiguous d; V read coalesced (512B per wave per t)
  {
    int d4 = tid * 4;
    int h = tid >> 5;
    float a0 = 0.f, a1 = 0.f, a2 = 0.f, a3 = 0.f;
#pragma unroll
    for (int t = 0; t < T_; t++) {
      int pos = W_ * n + t;
      if (pos < L_) {
        float w = sAttn[h * T_ + t];
        ushort4 v = *(const ushort4*)(kv + rowbase + (size_t)pos * 2048 + 1024 + d4);
        a0 += w * b2f(v.x); a1 += w * b2f(v.y);
        a2 += w * b2f(v.z); a3 += w * b2f(v.w);
      }
    }
    ushort4 ov;
    ov.x = f2b(a0); ov.y = f2b(a1); ov.z = f2b(a2); ov.w = f2b(a3);
    *(ushort4*)(o + (size_t)m * D_ + d4) = ov;
  }
}

// ---------------- fill output with log(0.5) ----------------
__global__ void fill_kernel(float* __restrict__ out) {
  int i = blockIdx.x * 256 + threadIdx.x;
  out[i] = -0.69314718055994531f;
}

// ---------------- fused head: o(bf16) @ Wc^T + bc -> log_softmax, scattered ----------
__global__ __launch_bounds__(256)
void probs_kernel(const unsigned short* __restrict__ ob16, const float* __restrict__ Wc,
                  const float* __restrict__ bc, float* __restrict__ out) {
  const int wave = threadIdx.x >> 6, lane = threadIdx.x & 63;
  const int m = blockIdx.x * 4 + wave;  // grid exact: 3272*4 = 13088
  const unsigned short* f = ob16 + (size_t)m * D_;
  float s0 = 0.f, s1 = 0.f;
  for (int d = lane; d < D_; d += 64) {
    float v = b2f(f[d]);
    s0 += v * Wc[d];
    s1 += v * Wc[D_ + d];
  }
  for (int off = 32; off > 0; off >>= 1) {
    s0 += __shfl_down(s0, off);
    s1 += __shfl_down(s1, off);
  }
  if (lane == 0) {
    float p0 = s0 + bc[0], p1 = s1 + bc[1];
    float mx = fmaxf(p0, p1);
    float lse = mx + logf(expf(p0 - mx) + expf(p1 - mx));
    int b = m / NW_, n = m - b * NW_;
    size_t row = (size_t)b * L_ + (size_t)(W_ * n);
    out[row * 2 + 0] = p0 - lse;
    out[row * 2 + 1] = p1 - lse;
  }
}

extern "C" void kernel_launch(void* const* d_in, const int* in_sizes, int n_in,
                              void* d_out, int out_size, void* d_ws, size_t ws_size,
                              hipStream_t stream) {
  const float* x          = (const float*)d_in[0];
  const float* in_proj_w  = (const float*)d_in[1];
  const float* in_proj_b  = (const float*)d_in[2];
  const float* out_proj_w = (const float*)d_in[3];
  const float* out_proj_b = (const float*)d_in[4];
  const float* out_w      = (const float*)d_in[5];
  const float* out_b      = (const float*)d_in[6];
  float* out = (float*)d_out;

  // workspace layout (~438 MB):
  //   [0, 128MB)        x_bf16  -- dead after kv GEMM; reused for qout/obuf
  //   [128MB, +6MB)     in_proj_w bf16 (wq|wk|wv)
  //   [+2MB)            Wc (2x1024 f32) + bc (2 f32)
  //   [+27MB)           xq (gathered centers, padded to MQP rows)
  //   [+256MB)          kv = K|V bf16, (B*L) x 2048
  char* ws = (char*)d_ws;
  unsigned short* xbf  = (unsigned short*)(ws);
  unsigned short* win  = (unsigned short*)(ws + 134217728);
  float*          Wc   = (float*)(ws + 140509184);
  float*          bc   = (float*)(ws + 140509184 + 8192);
  unsigned short* xq   = (unsigned short*)(ws + 142606336);
  unsigned short* kvb  = (unsigned short*)(ws + 169607168);
  unsigned short* qout = (unsigned short*)(ws);              // aliases dead xbf
  unsigned short* obuf = (unsigned short*)(ws + 27262976);

  cvt_kernel<<<65536, 256, 0, stream>>>(x, xbf, 16777216);
  cvt_kernel<<<3072, 256, 0, stream>>>(in_proj_w, win, 786432);
  wc_kernel<<<8, 256, 0, stream>>>(out_w, out_proj_w, out_proj_b, out_b, Wc, bc);
  gather_q_kernel<<<MQP, 128, 0, stream>>>(xbf, xq);

  dim3 gkv(16, 512);  // x = col tile (fastest), y = row tile; M=65536, N=2048 (K|V)
  gemm_bt_kernel<0><<<gkv, 256, 0, stream>>>(xbf, win + 1048576, kvb,
                                             in_proj_b + 1024, 2048, 1024);
  dim3 gq(8, 103);    // M=13184, N=1024
  gemm_bt_kernel<0><<<gq, 256, 0, stream>>>(xq, win, qout, in_proj_b, 1024, 1024);

  attn_kernel<<<MQ, 256, 0, stream>>>(qout, kvb, obuf);

  fill_kernel<<<512, 256, 0, stream>>>(out);  // exactly out_size=131072 floats
  probs_kernel<<<3272, 256, 0, stream>>>(obuf, Wc, bc, out);
}

// Round 4
// 969.956 us; speedup vs baseline: 1.1156x; 1.0667x over previous
//
#include <hip/hip_runtime.h>

#define B_  32
#define L_  2048
#define D_  1024
#define NW_ 409
#define W_  5
#define T_  11
#define H_  8
#define HD_ 128
#define MQ  (B_*NW_)   // 13088
#define MQP 13184      // 103*128 (padded M for q GEMM)

typedef __attribute__((ext_vector_type(16))) float f32x16;
typedef __attribute__((ext_vector_type(8))) __bf16 bf16x8;

__device__ __forceinline__ float b2f(unsigned short u) {
  union { unsigned int i; float f; } x; x.i = ((unsigned int)u) << 16; return x.f;
}
__device__ __forceinline__ unsigned short f2b(float f) {
  union { float f; unsigned int i; } x; x.f = f;
  unsigned int r = (x.i + 0x7FFFu + ((x.i >> 16) & 1u)) >> 16;
  return (unsigned short)r;
}
__device__ __forceinline__ float2 bf2x(unsigned int u) {
  union { unsigned int i; float f; } lo, hi;
  lo.i = u << 16; hi.i = u & 0xffff0000u;
  return make_float2(lo.f, hi.f);
}

__device__ __forceinline__ void async_copy16(const void* g, void* l) {
  __builtin_amdgcn_global_load_lds(
      (const __attribute__((address_space(1))) void*)g,
      (__attribute__((address_space(3))) void*)l, 16, 0, 0);
}

// ---------------- fp32 -> bf16 convert + fused center-row gather ----------------
__global__ void cvt_gather_kernel(const float* __restrict__ in,
                                  unsigned short* __restrict__ out,
                                  unsigned short* __restrict__ xq) {
  int i = blockIdx.x * 256 + threadIdx.x;   // 16777216 float4 groups
  float4 v = ((const float4*)in)[i];
  ushort4 o;
  o.x = f2b(v.x); o.y = f2b(v.y); o.z = f2b(v.z); o.w = f2b(v.w);
  ((ushort4*)out)[i] = o;
  int row = i >> 8, col4 = i & 255;
  int l = row & 2047, b = row >> 11;
  if (l >= 5 && l <= 2045 && (l % 5) == 0) {   // center rows l = 5n+5
    int n = l / 5 - 1;
    ((ushort4*)(xq + (size_t)(b * NW_ + n) * D_))[col4] = o;
  }
  // xq pad rows (13088..13183) stay poisoned: 0xAAAA bf16 = +-2^-42, harmless;
  // the q-GEMM rows they produce are never read (attn grid = MQ).
}

// ---------------- plain fp32 -> bf16 convert ----------------
__global__ void cvt_kernel(const float* __restrict__ in,
                           unsigned short* __restrict__ out, int n4) {
  int i = blockIdx.x * 256 + threadIdx.x;
  if (i >= n4) return;
  float4 v = ((const float4*)in)[i];
  ushort4 o;
  o.x = f2b(v.x); o.y = f2b(v.y); o.z = f2b(v.z); o.w = f2b(v.w);
  ((ushort4*)out)[i] = o;
}

// ---------------- fused head weights: Wc = out_w @ out_proj_w, bc = out_w@opb + ob ----
__global__ void wc_kernel(const float* __restrict__ ow, const float* __restrict__ opw,
                          const float* __restrict__ opb, const float* __restrict__ ob,
                          float* __restrict__ Wc, float* __restrict__ bc) {
  int d = blockIdx.x * 256 + threadIdx.x;   // 0..2047; c = d>>10
  int c = d >> 10, dd = d & 1023;
  float acc = 0.f;
  for (int e = 0; e < D_; e++) acc += ow[c * D_ + e] * opw[e * D_ + dd];
  Wc[d] = acc;
  if (d < 2) {
    float s = ob[d];
    for (int e = 0; e < D_; e++) s += ow[d * D_ + e] * opb[e];
    bc[d] = s;
  }
}

// ---------------- NT bf16 GEMM, BK=64, 32x32x16 MFMA ----------------
// C[M,N] = A[M,K] @ Bw[N,K]^T (+bias[N]); 128x128 tile, 4 waves 2x2, each wave
// 2x2 tiles of 32x32. LDS slot c holds chunk (r=c>>3, kc=((c&7)-r)&7); chunk
// (r,c8) read at slot r*8+((c8+r)&7) -> consecutive-8-lane groups cover all 8
// bank-quads (conflict-free). A/B frag: m|n=lane&31, k=kc16*16+(lane>>5)*8+j.
// C/D frag (m74/m101): col=lane&31, row=(reg&3)+8*(reg>>2)+4*(lane>>5).
__global__ __launch_bounds__(256)
void gemm_bt_kernel(const unsigned short* __restrict__ A,
                    const unsigned short* __restrict__ Bw,
                    unsigned short* __restrict__ C,
                    const float* __restrict__ bias,
                    int N, int K) {
  __shared__ unsigned short sA[128 * 64];
  __shared__ unsigned short sB[128 * 64];
  const int tid = threadIdx.x;
  const int row0 = blockIdx.y * 128;
  const int col0 = blockIdx.x * 128;  // x fastest: col tiles share A-tile in L2
  const int wave = tid >> 6, lane = tid & 63;
  const int wm = wave & 1, wn = wave >> 1;
  const int l31 = lane & 31, lh = lane >> 5;

  int src_r[4], src_kc[4];
#pragma unroll
  for (int u = 0; u < 4; u++) {
    int c = tid + 256 * u;
    src_r[u]  = c >> 3;
    src_kc[u] = ((c & 7) - (c >> 3)) & 7;
  }

  int offA[4][2], offB[4][2];
#pragma unroll
  for (int kc = 0; kc < 4; kc++) {
#pragma unroll
    for (int i = 0; i < 2; i++) {
      int c8 = kc * 2 + lh;
      int ra = wm * 64 + i * 32 + l31;
      offA[kc][i] = (ra * 8 + ((c8 + ra) & 7)) * 8;
      int rb = wn * 64 + i * 32 + l31;
      offB[kc][i] = (rb * 8 + ((c8 + rb) & 7)) * 8;
    }
  }

  f32x16 acc[2][2];
#pragma unroll
  for (int i = 0; i < 2; i++)
#pragma unroll
    for (int j = 0; j < 2; j++) acc[i][j] = (f32x16)0.0f;

  const unsigned short* Asrc[4];
  const unsigned short* Bsrc[4];
#pragma unroll
  for (int u = 0; u < 4; u++) {
    Asrc[u] = A  + (size_t)(row0 + src_r[u]) * K + src_kc[u] * 8;
    Bsrc[u] = Bw + (size_t)(col0 + src_r[u]) * K + src_kc[u] * 8;
  }

  for (int kt = 0; kt < K; kt += 64) {
#pragma unroll
    for (int u = 0; u < 4; u++) {
      async_copy16(Asrc[u] + kt, &sA[(tid + 256 * u) * 8]);
      async_copy16(Bsrc[u] + kt, &sB[(tid + 256 * u) * 8]);
    }
    __syncthreads();
#pragma unroll
    for (int kc = 0; kc < 4; kc++) {
      bf16x8 a0 = *(const bf16x8*)&sA[offA[kc][0]];
      bf16x8 a1 = *(const bf16x8*)&sA[offA[kc][1]];
      bf16x8 b0 = *(const bf16x8*)&sB[offB[kc][0]];
      bf16x8 b1 = *(const bf16x8*)&sB[offB[kc][1]];
      acc[0][0] = __builtin_amdgcn_mfma_f32_32x32x16_bf16(a0, b0, acc[0][0], 0, 0, 0);
      acc[0][1] = __builtin_amdgcn_mfma_f32_32x32x16_bf16(a0, b1, acc[0][1], 0, 0, 0);
      acc[1][0] = __builtin_amdgcn_mfma_f32_32x32x16_bf16(a1, b0, acc[1][0], 0, 0, 0);
      acc[1][1] = __builtin_amdgcn_mfma_f32_32x32x16_bf16(a1, b1, acc[1][1], 0, 0, 0);
    }
    __syncthreads();
  }

#pragma unroll
  for (int i = 0; i < 2; i++) {
#pragma unroll
    for (int j = 0; j < 2; j++) {
      int gc = col0 + wn * 64 + j * 32 + l31;
      float bv = bias ? bias[gc] : 0.0f;
#pragma unroll
      for (int r = 0; r < 16; r++) {
        int gr = row0 + wm * 64 + i * 32 + (r & 3) + 8 * (r >> 2) + 4 * lh;
        C[(size_t)gr * N + gc] = f2b(acc[i][j][r] + bv);
      }
    }
  }
}

// ---------------- windowed attention + fused classifier head ----------------
// K/V read straight from global (each used once per window; L2 serves the 2.2x
// inter-window overlap). o stays in registers; head dot + log_softmax fused.
__global__ __launch_bounds__(256)
void attn_kernel(const unsigned short* __restrict__ q,
                 const unsigned short* __restrict__ kv,
                 const float* __restrict__ Wc, const float* __restrict__ bc,
                 float* __restrict__ out) {
  __shared__ unsigned short sQ[D_];
  __shared__ float sAttn[H_ * T_];
  __shared__ float sRed[8];
  const int m = blockIdx.x;       // b*NW_+n
  const int b = m / NW_, n = m - b * NW_;
  const int tid = threadIdx.x;
  const size_t rowbase = (size_t)b * L_ * 2048;

  if (tid < 128)
    ((uint4*)sQ)[tid] = ((const uint4*)(q + (size_t)m * D_))[tid];
  __syncthreads();

  // scores: 16 lanes per (h,t); lane reads 8 bf16 of K (256B contiguous/pair)
  {
    const int s = tid & 15, p0 = tid >> 4;
#pragma unroll
    for (int r = 0; r < 6; r++) {
      int pair = r * 16 + p0;           // 0..95, 88 real
      float sc = 0.f;
      if (pair < H_ * T_) {
        int h = pair / T_, t = pair - h * T_;
        int pos = W_ * n + t;
        if (pos < L_) {
          uint4 k4 = *(const uint4*)(kv + rowbase + (size_t)pos * 2048 + h * HD_ + s * 8);
          uint4 q4 = *(const uint4*)(sQ + h * HD_ + s * 8);
          float2 a0 = bf2x(q4.x), b0 = bf2x(k4.x);
          float2 a1 = bf2x(q4.y), b1 = bf2x(k4.y);
          float2 a2 = bf2x(q4.z), b2 = bf2x(k4.z);
          float2 a3 = bf2x(q4.w), b3 = bf2x(k4.w);
          sc = a0.x * b0.x + a0.y * b0.y + a1.x * b1.x + a1.y * b1.y
             + a2.x * b2.x + a2.y * b2.y + a3.x * b3.x + a3.y * b3.y;
        }
      }
      sc += __shfl_down(sc, 8);
      sc += __shfl_down(sc, 4);
      sc += __shfl_down(sc, 2);
      sc += __shfl_down(sc, 1);
      if (pair < H_ * T_ && s == 0)
        sAttn[pair] = sc * 0.08838834764831845f;  // 1/sqrt(128)
    }
  }
  __syncthreads();

  if (tid < H_) {
    float sv[T_];
    float mx = -1e30f;
    for (int t = 0; t < T_; t++) { sv[t] = sAttn[tid * T_ + t]; mx = fmaxf(mx, sv[t]); }
    float sum = 0.f;
    for (int t = 0; t < T_; t++) { sv[t] = expf(sv[t] - mx); sum += sv[t]; }
    float inv = 1.f / sum;
    for (int t = 0; t < T_; t++) sAttn[tid * T_ + t] = sv[t] * inv;
  }
  __syncthreads();

  // o: thread owns 4 contiguous d; V read coalesced; then fused head dot
  {
    int d4 = tid * 4;
    int h = tid >> 5;
    float a0 = 0.f, a1 = 0.f, a2 = 0.f, a3 = 0.f;
#pragma unroll
    for (int t = 0; t < T_; t++) {
      int pos = W_ * n + t;
      if (pos < L_) {
        float w = sAttn[h * T_ + t];
        ushort4 v = *(const ushort4*)(kv + rowbase + (size_t)pos * 2048 + 1024 + d4);
        a0 += w * b2f(v.x); a1 += w * b2f(v.y);
        a2 += w * b2f(v.z); a3 += w * b2f(v.w);
      }
    }
    float4 w0 = ((const float4*)Wc)[tid];
    float4 w1 = ((const float4*)Wc)[256 + tid];
    float p0 = a0 * w0.x + a1 * w0.y + a2 * w0.z + a3 * w0.w;
    float p1 = a0 * w1.x + a1 * w1.y + a2 * w1.z + a3 * w1.w;
#pragma unroll
    for (int off = 32; off > 0; off >>= 1) {
      p0 += __shfl_down(p0, off);
      p1 += __shfl_down(p1, off);
    }
    const int wave = tid >> 6, lane = tid & 63;
    if (lane == 0) { sRed[wave] = p0; sRed[4 + wave] = p1; }
  }
  __syncthreads();

  if (tid == 0) {
    float s0 = sRed[0] + sRed[1] + sRed[2] + sRed[3] + bc[0];
    float s1 = sRed[4] + sRed[5] + sRed[6] + sRed[7] + bc[1];
    float mx = fmaxf(s0, s1);
    float lse = mx + logf(expf(s0 - mx) + expf(s1 - mx));
    size_t row = (size_t)b * L_ + (size_t)(W_ * n);
    out[row * 2 + 0] = s0 - lse;
    out[row * 2 + 1] = s1 - lse;
  }
}

// ---------------- fill output with log(0.5) ----------------
__global__ void fill_kernel(float* __restrict__ out) {
  int i = blockIdx.x * 256 + threadIdx.x;
  out[i] = -0.69314718055994531f;
}

extern "C" void kernel_launch(void* const* d_in, const int* in_sizes, int n_in,
                              void* d_out, int out_size, void* d_ws, size_t ws_size,
                              hipStream_t stream) {
  const float* x          = (const float*)d_in[0];
  const float* in_proj_w  = (const float*)d_in[1];
  const float* in_proj_b  = (const float*)d_in[2];
  const float* out_proj_w = (const float*)d_in[3];
  const float* out_proj_b = (const float*)d_in[4];
  const float* out_w      = (const float*)d_in[5];
  const float* out_b      = (const float*)d_in[6];
  float* out = (float*)d_out;

  // workspace layout (~438 MB):
  //   [0, 128MB)        x_bf16  -- dead after kv GEMM; reused for qout
  //   [128MB, +6MB)     in_proj_w bf16 (wq|wk|wv)
  //   [+2MB)            Wc (2x1024 f32) + bc (2 f32)
  //   [+27MB)           xq (gathered centers, MQP rows; pad rows poison-ok)
  //   [+256MB)          kv = K|V bf16, (B*L) x 2048
  char* ws = (char*)d_ws;
  unsigned short* xbf  = (unsigned short*)(ws);
  unsigned short* win  = (unsigned short*)(ws + 134217728);
  float*          Wc   = (float*)(ws + 140509184);
  float*          bc   = (float*)(ws + 140509184 + 8192);
  unsigned short* xq   = (unsigned short*)(ws + 142606336);
  unsigned short* kvb  = (unsigned short*)(ws + 169607168);
  unsigned short* qout = (unsigned short*)(ws);              // aliases dead xbf

  cvt_gather_kernel<<<65536, 256, 0, stream>>>(x, xbf, xq);
  cvt_kernel<<<3072, 256, 0, stream>>>(in_proj_w, win, 786432);
  wc_kernel<<<8, 256, 0, stream>>>(out_w, out_proj_w, out_proj_b, out_b, Wc, bc);

  dim3 gkv(16, 512);  // x = col tile (fastest), y = row tile; M=65536, N=2048 (K|V)
  gemm_bt_kernel<<<gkv, 256, 0, stream>>>(xbf, win + 1048576, kvb,
                                          in_proj_b + 1024, 2048, 1024);
  dim3 gq(8, 103);    // M=13184, N=1024
  gemm_bt_kernel<<<gq, 256, 0, stream>>>(xq, win, qout, in_proj_b, 1024, 1024);

  fill_kernel<<<512, 256, 0, stream>>>(out);  // exactly out_size=131072 floats
  attn_kernel<<<MQ, 256, 0, stream>>>(qout, kvb, Wc, bc, out);
}

// Round 5
// 911.875 us; speedup vs baseline: 1.1866x; 1.0637x over previous
//
#include <hip/hip_runtime.h>

#define B_  32
#define L_  2048
#define D_  1024
#define NW_ 409
#define W_  5
#define T_  11
#define H_  8
#define HD_ 128
#define MQ  (B_*NW_)   // 13088
#define MQP 13184      // 103*128 (padded M for q GEMM)

typedef __attribute__((ext_vector_type(4))) float f32x4;
typedef __attribute__((ext_vector_type(16))) float f32x16;
typedef __attribute__((ext_vector_type(8))) __bf16 bf16x8;

__device__ __forceinline__ float b2f(unsigned short u) {
  union { unsigned int i; float f; } x; x.i = ((unsigned int)u) << 16; return x.f;
}
__device__ __forceinline__ unsigned short f2b(float f) {
  union { float f; unsigned int i; } x; x.f = f;
  unsigned int r = (x.i + 0x7FFFu + ((x.i >> 16) & 1u)) >> 16;
  return (unsigned short)r;
}
__device__ __forceinline__ float2 bf2x(unsigned int u) {
  union { unsigned int i; float f; } lo, hi;
  lo.i = u << 16; hi.i = u & 0xffff0000u;
  return make_float2(lo.f, hi.f);
}
// two f32x4 -> bf16x8 (RNE, hardware cvt)
__device__ __forceinline__ bf16x8 cvt8(f32x4 a, f32x4 b) {
  bf16x8 r;
  r[0] = (__bf16)a[0]; r[1] = (__bf16)a[1]; r[2] = (__bf16)a[2]; r[3] = (__bf16)a[3];
  r[4] = (__bf16)b[0]; r[5] = (__bf16)b[1]; r[6] = (__bf16)b[2]; r[7] = (__bf16)b[3];
  return r;
}

__device__ __forceinline__ void async_copy16(const void* g, void* l) {
  __builtin_amdgcn_global_load_lds(
      (const __attribute__((address_space(1))) void*)g,
      (__attribute__((address_space(3))) void*)l, 16, 0, 0);
}

// ---------------- plain fp32 -> bf16 convert (weights only) ----------------
__global__ void cvt_kernel(const float* __restrict__ in,
                           unsigned short* __restrict__ out, int n4) {
  int i = blockIdx.x * 256 + threadIdx.x;
  if (i >= n4) return;
  float4 v = ((const float4*)in)[i];
  ushort4 o;
  o.x = f2b(v.x); o.y = f2b(v.y); o.z = f2b(v.z); o.w = f2b(v.w);
  ((ushort4*)out)[i] = o;
}

// ---------------- gather+convert query center rows from fp32 x ----------------
__global__ void gather_q_kernel(const float* __restrict__ x,
                                unsigned short* __restrict__ xq) {
  int m = blockIdx.x;            // 0..MQ-1 (pad rows of xq left poisoned: unused)
  int t = threadIdx.x;           // 128 threads x 2 float4
  int b = m / NW_, n = m - b * NW_;
  const float4* src = (const float4*)(x + ((size_t)b * L_ + (size_t)(W_ * n + W_)) * D_);
#pragma unroll
  for (int u = 0; u < 2; u++) {
    float4 v = src[t + 128 * u];
    ushort4 o;
    o.x = f2b(v.x); o.y = f2b(v.y); o.z = f2b(v.z); o.w = f2b(v.w);
    ((ushort4*)(xq + (size_t)m * D_))[t + 128 * u] = o;
  }
}

// ---------------- fused head weights, split-K ----------------
// Wcp[eb][d] = sum over e in [eb*64, eb*64+64) of ow[c,e]*opw[e,dd]
__global__ void wc_part_kernel(const float* __restrict__ ow, const float* __restrict__ opw,
                               float* __restrict__ Wcp) {
  int eb = blockIdx.x >> 3, seg = blockIdx.x & 7;   // 16 x 8 blocks
  int d = seg * 256 + threadIdx.x;                  // 0..2047
  int c = d >> 10, dd = d & 1023;
  float acc = 0.f;
  int e0 = eb * 64;
#pragma unroll 8
  for (int e = e0; e < e0 + 64; e++) acc += ow[c * D_ + e] * opw[e * D_ + dd];
  Wcp[eb * 2048 + d] = acc;
}
__global__ void wc_reduce_kernel(const float* __restrict__ Wcp,
                                 const float* __restrict__ ow, const float* __restrict__ opb,
                                 const float* __restrict__ ob,
                                 float* __restrict__ Wc, float* __restrict__ bc) {
  int d = blockIdx.x * 256 + threadIdx.x;
  float s = 0.f;
#pragma unroll
  for (int eb = 0; eb < 16; eb++) s += Wcp[eb * 2048 + d];
  Wc[d] = s;
  if (blockIdx.x == 0 && threadIdx.x < 128) {
    int c = threadIdx.x >> 6, lane = threadIdx.x & 63;
    float p = 0.f;
#pragma unroll
    for (int j = 0; j < 16; j++) p += ow[c * D_ + lane + 64 * j] * opb[lane + 64 * j];
#pragma unroll
    for (int off = 32; off > 0; off >>= 1) p += __shfl_down(p, off);
    if (lane == 0) bc[c] = p + ob[c];
  }
}

// ---------------- NT GEMM, BK=64, 32x32x16 MFMA; A fp32 (in-reg cvt) or bf16 ----
// C[M,N] = A[M,K] @ Bw[N,K]^T (+bias[N]); 128x128 tile, 4 waves 2x2, wave does
// 2x2 32x32 tiles. B (bf16): slot c holds (r=c>>3, kc=((c&7)-r)&7); read quad
// (c8+rb)&7 cycles with rb -> conflict-free. A fp32: 16 slots/row of 4 floats,
// slot s of row r holds cf=(s-r)&15; read quad (2c8+ra)&7 cycles -> free.
template<bool AF32>
__global__ __launch_bounds__(256)
void gemm_bt_kernel(const void* __restrict__ Av,
                    const unsigned short* __restrict__ Bw,
                    unsigned short* __restrict__ C,
                    const float* __restrict__ bias,
                    int N, int K) {
  constexpr int ABYTES = AF32 ? 4 : 2;
  __shared__ __align__(16) unsigned char sAraw[128 * 64 * ABYTES];
  __shared__ unsigned short sB[128 * 64];
  const int tid = threadIdx.x;
  const int row0 = blockIdx.y * 128;
  const int col0 = blockIdx.x * 128;  // x fastest: col tiles share A-tile in L2
  const int wave = tid >> 6, lane = tid & 63;
  const int wm = wave & 1, wn = wave >> 1;
  const int l31 = lane & 31, lh = lane >> 5;

  // ---- B staging coords (1024 16B chunks) ----
  const unsigned short* Bsrc[4];
#pragma unroll
  for (int u = 0; u < 4; u++) {
    int c = tid + 256 * u;
    int r = c >> 3, kc = ((c & 7) - r) & 7;
    Bsrc[u] = Bw + (size_t)(col0 + r) * K + kc * 8;
  }
  // ---- A staging coords ----
  const float* AsrcF[8];
  const unsigned short* AsrcH[4];
  if constexpr (AF32) {
    const float* A = (const float*)Av;
#pragma unroll
    for (int u = 0; u < 8; u++) {
      int c = tid + 256 * u;
      int r = c >> 4, cf = ((c & 15) - r) & 15;
      AsrcF[u] = A + (size_t)(row0 + r) * K + cf * 4;
    }
  } else {
    const unsigned short* A = (const unsigned short*)Av;
#pragma unroll
    for (int u = 0; u < 4; u++) {
      int c = tid + 256 * u;
      int r = c >> 3, kc = ((c & 7) - r) & 7;
      AsrcH[u] = A + (size_t)(row0 + r) * K + kc * 8;
    }
  }

  // ---- fragment read offsets ----
  int offB[4][2];        // [kc][j] in shorts
  int offA16[4][2];      // bf16 path, in shorts
  int offA32a[4][2], offA32b[4][2];  // fp32 path, in floats
#pragma unroll
  for (int kc = 0; kc < 4; kc++) {
    int c8 = kc * 2 + lh;
#pragma unroll
    for (int i = 0; i < 2; i++) {
      int rb = wn * 64 + i * 32 + l31;
      offB[kc][i] = (rb * 8 + ((c8 + rb) & 7)) * 8;
      int ra = wm * 64 + i * 32 + l31;
      offA16[kc][i] = (ra * 8 + ((c8 + ra) & 7)) * 8;
      offA32a[kc][i] = ra * 64 + ((2 * c8 + ra) & 15) * 4;
      offA32b[kc][i] = ra * 64 + ((2 * c8 + 1 + ra) & 15) * 4;
    }
  }

  f32x16 acc[2][2];
#pragma unroll
  for (int i = 0; i < 2; i++)
#pragma unroll
    for (int j = 0; j < 2; j++) acc[i][j] = (f32x16)0.0f;

  for (int kt = 0; kt < K; kt += 64) {
    if constexpr (AF32) {
#pragma unroll
      for (int u = 0; u < 8; u++)
        async_copy16(AsrcF[u] + kt, sAraw + (tid + 256 * u) * 16);
    } else {
#pragma unroll
      for (int u = 0; u < 4; u++)
        async_copy16(AsrcH[u] + kt, sAraw + (tid + 256 * u) * 16);
    }
#pragma unroll
    for (int u = 0; u < 4; u++)
      async_copy16(Bsrc[u] + kt, &sB[(tid + 256 * u) * 8]);
    __syncthreads();
#pragma unroll
    for (int kc = 0; kc < 4; kc++) {
      bf16x8 a0, a1;
      if constexpr (AF32) {
        const float* sAf = (const float*)sAraw;
        a0 = cvt8(*(const f32x4*)&sAf[offA32a[kc][0]], *(const f32x4*)&sAf[offA32b[kc][0]]);
        a1 = cvt8(*(const f32x4*)&sAf[offA32a[kc][1]], *(const f32x4*)&sAf[offA32b[kc][1]]);
      } else {
        const unsigned short* sAh = (const unsigned short*)sAraw;
        a0 = *(const bf16x8*)&sAh[offA16[kc][0]];
        a1 = *(const bf16x8*)&sAh[offA16[kc][1]];
      }
      bf16x8 b0 = *(const bf16x8*)&sB[offB[kc][0]];
      bf16x8 b1 = *(const bf16x8*)&sB[offB[kc][1]];
      acc[0][0] = __builtin_amdgcn_mfma_f32_32x32x16_bf16(a0, b0, acc[0][0], 0, 0, 0);
      acc[0][1] = __builtin_amdgcn_mfma_f32_32x32x16_bf16(a0, b1, acc[0][1], 0, 0, 0);
      acc[1][0] = __builtin_amdgcn_mfma_f32_32x32x16_bf16(a1, b0, acc[1][0], 0, 0, 0);
      acc[1][1] = __builtin_amdgcn_mfma_f32_32x32x16_bf16(a1, b1, acc[1][1], 0, 0, 0);
    }
    __syncthreads();
  }

  // C/D frag (m74/m101): col=lane&31, row=(reg&3)+8*(reg>>2)+4*(lane>>5)
#pragma unroll
  for (int i = 0; i < 2; i++) {
#pragma unroll
    for (int j = 0; j < 2; j++) {
      int gc = col0 + wn * 64 + j * 32 + l31;
      float bv = bias ? bias[gc] : 0.0f;
#pragma unroll
      for (int r = 0; r < 16; r++) {
        int gr = row0 + wm * 64 + i * 32 + (r & 3) + 8 * (r >> 2) + 4 * lh;
        C[(size_t)gr * N + gc] = f2b(acc[i][j][r] + bv);
      }
    }
  }
}

// ---------------- windowed attention + fused classifier head ----------------
// XCD-contiguity swizzle: blocks dispatch round-robin across 8 XCDs; map so
// XCD k owns contiguous windows [k*1636,(k+1)*1636) -> 2.2x KV overlap hits L2.
__global__ __launch_bounds__(256)
void attn_kernel(const unsigned short* __restrict__ q,
                 const unsigned short* __restrict__ kv,
                 const float* __restrict__ Wc, const float* __restrict__ bc,
                 float* __restrict__ out) {
  __shared__ unsigned short sQ[D_];
  __shared__ float sAttn[H_ * T_];
  __shared__ float sRed[8];
  const int blk = blockIdx.x;
  const int m = (blk >> 3) + (blk & 7) * 1636;   // 13088 = 8*1636
  const int b = m / NW_, n = m - b * NW_;
  const int tid = threadIdx.x;
  const size_t rowbase = (size_t)b * L_ * 2048;

  if (tid < 128)
    ((uint4*)sQ)[tid] = ((const uint4*)(q + (size_t)m * D_))[tid];
  __syncthreads();

  // scores: 16 lanes per (h,t); lane reads 8 bf16 of K (256B contiguous/pair)
  {
    const int s = tid & 15, p0 = tid >> 4;
#pragma unroll
    for (int r = 0; r < 6; r++) {
      int pair = r * 16 + p0;           // 0..95, 88 real
      float sc = 0.f;
      if (pair < H_ * T_) {
        int h = pair / T_, t = pair - h * T_;
        int pos = W_ * n + t;
        if (pos < L_) {
          uint4 k4 = *(const uint4*)(kv + rowbase + (size_t)pos * 2048 + h * HD_ + s * 8);
          uint4 q4 = *(const uint4*)(sQ + h * HD_ + s * 8);
          float2 a0 = bf2x(q4.x), b0 = bf2x(k4.x);
          float2 a1 = bf2x(q4.y), b1 = bf2x(k4.y);
          float2 a2 = bf2x(q4.z), b2 = bf2x(k4.z);
          float2 a3 = bf2x(q4.w), b3 = bf2x(k4.w);
          sc = a0.x * b0.x + a0.y * b0.y + a1.x * b1.x + a1.y * b1.y
             + a2.x * b2.x + a2.y * b2.y + a3.x * b3.x + a3.y * b3.y;
        }
      }
      sc += __shfl_down(sc, 8);
      sc += __shfl_down(sc, 4);
      sc += __shfl_down(sc, 2);
      sc += __shfl_down(sc, 1);
      if (pair < H_ * T_ && s == 0)
        sAttn[pair] = sc * 0.08838834764831845f;  // 1/sqrt(128)
    }
  }
  __syncthreads();

  if (tid < H_) {
    float sv[T_];
    float mx = -1e30f;
    for (int t = 0; t < T_; t++) { sv[t] = sAttn[tid * T_ + t]; mx = fmaxf(mx, sv[t]); }
    float sum = 0.f;
    for (int t = 0; t < T_; t++) { sv[t] = expf(sv[t] - mx); sum += sv[t]; }
    float inv = 1.f / sum;
    for (int t = 0; t < T_; t++) sAttn[tid * T_ + t] = sv[t] * inv;
  }
  __syncthreads();

  // o: thread owns 4 contiguous d; V read coalesced; then fused head dot
  {
    int d4 = tid * 4;
    int h = tid >> 5;
    float a0 = 0.f, a1 = 0.f, a2 = 0.f, a3 = 0.f;
#pragma unroll
    for (int t = 0; t < T_; t++) {
      int pos = W_ * n + t;
      if (pos < L_) {
        float w = sAttn[h * T_ + t];
        ushort4 v = *(const ushort4*)(kv + rowbase + (size_t)pos * 2048 + 1024 + d4);
        a0 += w * b2f(v.x); a1 += w * b2f(v.y);
        a2 += w * b2f(v.z); a3 += w * b2f(v.w);
      }
    }
    float4 w0 = ((const float4*)Wc)[tid];
    float4 w1 = ((const float4*)Wc)[256 + tid];
    float p0 = a0 * w0.x + a1 * w0.y + a2 * w0.z + a3 * w0.w;
    float p1 = a0 * w1.x + a1 * w1.y + a2 * w1.z + a3 * w1.w;
#pragma unroll
    for (int off = 32; off > 0; off >>= 1) {
      p0 += __shfl_down(p0, off);
      p1 += __shfl_down(p1, off);
    }
    const int wv = tid >> 6, lane = tid & 63;
    if (lane == 0) { sRed[wv] = p0; sRed[4 + wv] = p1; }
  }
  __syncthreads();

  if (tid == 0) {
    float s0 = sRed[0] + sRed[1] + sRed[2] + sRed[3] + bc[0];
    float s1 = sRed[4] + sRed[5] + sRed[6] + sRed[7] + bc[1];
    float mx = fmaxf(s0, s1);
    float lse = mx + logf(expf(s0 - mx) + expf(s1 - mx));
    size_t row = (size_t)b * L_ + (size_t)(W_ * n);
    out[row * 2 + 0] = s0 - lse;
    out[row * 2 + 1] = s1 - lse;
  }
}

// ---------------- fill output with log(0.5) ----------------
__global__ void fill_kernel(float* __restrict__ out) {
  int i = blockIdx.x * 256 + threadIdx.x;
  out[i] = -0.69314718055994531f;
}

extern "C" void kernel_launch(void* const* d_in, const int* in_sizes, int n_in,
                              void* d_out, int out_size, void* d_ws, size_t ws_size,
                              hipStream_t stream) {
  const float* x          = (const float*)d_in[0];
  const float* in_proj_w  = (const float*)d_in[1];
  const float* in_proj_b  = (const float*)d_in[2];
  const float* out_proj_w = (const float*)d_in[3];
  const float* out_proj_b = (const float*)d_in[4];
  const float* out_w      = (const float*)d_in[5];
  const float* out_b      = (const float*)d_in[6];
  float* out = (float*)d_out;

  // workspace (~336 MB):
  //   [0, 32MB)    qout (MQP x 1024 bf16)
  //   [32MB)       xq   (MQP x 1024 bf16; pad rows poison-ok)
  //   [64MB)       in_proj_w bf16 (wq|wk|wv)
  //   [72MB)       Wc (2x1024 f32), bc, Wcp (16x2048 f32)
  //   [80MB)       kv = K|V bf16, (B*L) x 2048 (256MB)
  char* ws = (char*)d_ws;
  unsigned short* qout = (unsigned short*)(ws);
  unsigned short* xq   = (unsigned short*)(ws + 33554432);
  unsigned short* win  = (unsigned short*)(ws + 67108864);
  float*          Wc   = (float*)(ws + 75497472);
  float*          bc   = (float*)(ws + 75505664);
  float*          Wcp  = (float*)(ws + 75513856);
  unsigned short* kvb  = (unsigned short*)(ws + 83886080);

  cvt_kernel<<<3072, 256, 0, stream>>>(in_proj_w, win, 786432);
  gather_q_kernel<<<MQ, 128, 0, stream>>>(x, xq);
  wc_part_kernel<<<128, 256, 0, stream>>>(out_w, out_proj_w, Wcp);
  wc_reduce_kernel<<<8, 256, 0, stream>>>(Wcp, out_w, out_proj_b, out_b, Wc, bc);

  dim3 gkv(16, 512);  // N=2048 (K|V) x M=65536; A = fp32 x directly
  gemm_bt_kernel<true><<<gkv, 256, 0, stream>>>(x, win + 1048576, kvb,
                                                in_proj_b + 1024, 2048, 1024);
  dim3 gq(8, 103);    // M=13184, N=1024; A = bf16 xq
  gemm_bt_kernel<false><<<gq, 256, 0, stream>>>(xq, win, qout, in_proj_b, 1024, 1024);

  fill_kernel<<<512, 256, 0, stream>>>(out);  // exactly out_size=131072 floats
  attn_kernel<<<MQ, 256, 0, stream>>>(qout, kvb, Wc, bc, out);
}